// Round 7
// baseline (492.958 us; speedup 1.0000x reference)
//
#include <hip/hip_runtime.h>
#include <math.h>

#define D_MODEL 2048
#define NHEADS  16
#define HDIM    128
#define BATCH   2
#define SEQ     2048
#define MTOT    (BATCH*SEQ)   // 4096

typedef unsigned short u16;
typedef unsigned int   u32;
typedef __attribute__((ext_vector_type(8))) short  short8;
typedef __attribute__((ext_vector_type(8))) u16    ushort8;
typedef __attribute__((ext_vector_type(4))) u16    us4;
typedef __attribute__((ext_vector_type(4))) float  floatx4;

__device__ __forceinline__ u16 f2b(float f) {          // fp32 -> bf16 RNE
    u32 u = __float_as_uint(f);
    return (u16)((u + 0x7fffu + ((u >> 16) & 1u)) >> 16);
}
__device__ __forceinline__ float b2f(u16 b) {          // bf16 -> fp32 exact
    return __uint_as_float(((u32)b) << 16);
}
__device__ __forceinline__ void async16(void* lds, const void* g) {
    __builtin_amdgcn_global_load_lds(
        (const __attribute__((address_space(1))) u32*)g,
        (__attribute__((address_space(3))) u32*)lds, 16, 0, 0);
}

// ---------------------------------------------------------------------------
// fp32 -> bf16 conversion for x and the 4 weight matrices.
// ---------------------------------------------------------------------------
__global__ __launch_bounds__(256)
void f2b_kernel(const float* __restrict__ x,
                const float* __restrict__ wq, const float* __restrict__ wk,
                const float* __restrict__ wv, const float* __restrict__ wo,
                u16* __restrict__ xb, u16* __restrict__ wqb, u16* __restrict__ wkb,
                u16* __restrict__ wvb, u16* __restrict__ wob)
{
    const int bid = blockIdx.x;
    const float* src; u16* dst; int lb;
    if (bid < 4096) { src = x; dst = xb; lb = bid; }
    else {
        const int t = (bid - 4096) >> 11;
        lb = (bid - 4096) & 2047;
        src = (t == 0) ? wq : (t == 1) ? wk : (t == 2) ? wv : wo;
        dst = (t == 0) ? wqb : (t == 1) ? wkb : (t == 2) ? wvb : wob;
    }
    const size_t e = ((size_t)lb * 256 + threadIdx.x) * 8;
    const float4 a = *(const float4*)&src[e];
    const float4 b = *(const float4*)&src[e + 4];
    union { u16 u[8]; uint4 v; } o;
    o.u[0] = f2b(a.x); o.u[1] = f2b(a.y); o.u[2] = f2b(a.z); o.u[3] = f2b(a.w);
    o.u[4] = f2b(b.x); o.u[5] = f2b(b.y); o.u[6] = f2b(b.z); o.u[7] = f2b(b.w);
    *(uint4*)&dst[e] = o.v;
}

// ---------------------------------------------------------------------------
// Deep-pipelined bf16 MFMA GEMM: C = A[M,2048] @ W[N,2048]^T + bias.
// BM=128, BN=256, BK=64, 512 thr (8 waves; per-wave 128Mx32N).
// 4 phases per K-tile: {issue 1 stage group | ds_read frag subtile | 8 MFMA |
// s_barrier}; one counted vmcnt(3) gate per tile (never 0 until last tile).
// Stage groups per tile: A0(rows0-63,1 ld), A1(1), B0(even 16-col stripes, 2),
// B1(odd, 2). Issue calendar (race-free by phase-barrier dominance):
//   p1: A1(t+1)  p2: B1(t+1)  p3: A0(t+2)  p4: B0(t+2)
// LDS reads: af0,bf0 @p1; bf1 @p2; af1 @p3; p4 pure MFMA (frags cached).
// T2 swizzle chunk^=(row&7), inverse-swizzled global source, linear LDS dest.
// mode 0: fused QKV epilogue (N=6144; V written transposed [B,H,Dh,S]).
// mode 1: fp32 [M,2048] + bias (bq).
// ---------------------------------------------------------------------------
__global__ __launch_bounds__(512, 2)
void gemm8(const u16* __restrict__ A, const u16* __restrict__ W,
           const float* __restrict__ bq, const float* __restrict__ bk,
           const float* __restrict__ bv,
           u16* __restrict__ Qb, u16* __restrict__ Kb, u16* __restrict__ Vb,
           float* __restrict__ Cf, int mode)
{
    __shared__ __align__(16) u16 As[2][128 * 64];   // 2 x 16 KB
    __shared__ __align__(16) u16 Bs[2][256 * 64];   // 2 x 32 KB  -> 96 KB

    const int tid = threadIdx.x, lane = tid & 63, wn = tid >> 6;
    const int l15 = lane & 15, l4 = lane >> 4;
    const int cpx = (int)gridDim.x >> 3;            // bijective XCD swizzle
    const int swz = ((int)blockIdx.x & 7) * cpx + ((int)blockIdx.x >> 3);
    const int bm = swz & 31, bn = swz >> 5;
    const int m0 = bm * 128, n0 = bn * 256;

    const u16* Ag = A + (size_t)m0 * 2048;
    const u16* Wg = W + (size_t)n0 * 2048;
    const int lc = tid >> 3, ch = tid & 7;

    #define STA(buf, kt, mq_) {                                                 \
        const int row_ = (mq_) * 64 + lc;                                       \
        const int cs_ = ch ^ (row_ & 7);                                        \
        async16(&As[buf][row_ * 64 + ch * 8],                                   \
                Ag + (size_t)row_ * 2048 + (kt) * 64 + cs_ * 8); }
    #define STB(buf, kt, nsub) {                                               \
        _Pragma("unroll") for (int r_ = 0; r_ < 2; ++r_) {                      \
            const int col_ = (nsub) * 16 + (lc & 15) + (lc >> 4) * 32 + r_ * 128;\
            const int cs_ = ch ^ (col_ & 7);                                    \
            async16(&Bs[buf][col_ * 64 + ch * 8],                               \
                    Wg + (size_t)col_ * 2048 + (kt) * 64 + cs_ * 8); } }

    floatx4 acc[8][2];
    #pragma unroll
    for (int i = 0; i < 8; ++i)
        #pragma unroll
        for (int j = 0; j < 2; ++j) acc[i][j] = (floatx4){0.f, 0.f, 0.f, 0.f};

    short8 af[4][2], bf[2][2];

    #define LDA(mq_, buf) _Pragma("unroll") for (int i_ = 0; i_ < 4; ++i_) {    \
        const int row_ = (mq_) * 64 + i_ * 16 + l15;                            \
        _Pragma("unroll") for (int kk_ = 0; kk_ < 2; ++kk_) {                   \
            const int c_ = (kk_ * 4 + l4) ^ (row_ & 7);                         \
            af[i_][kk_] = *(const short8*)&As[buf][row_ * 64 + c_ * 8]; } }
    #define LDB(nq_, buf) {                                                     \
        const int col_ = wn * 32 + (nq_) * 16 + l15;                            \
        _Pragma("unroll") for (int kk_ = 0; kk_ < 2; ++kk_) {                   \
            const int c_ = (kk_ * 4 + l4) ^ (col_ & 7);                         \
            bf[nq_][kk_] = *(const short8*)&Bs[buf][col_ * 64 + c_ * 8]; } }
    #define MM(mq_, nq_) {                                                      \
        __builtin_amdgcn_s_setprio(1);                                          \
        _Pragma("unroll") for (int i_ = 0; i_ < 4; ++i_)                        \
        _Pragma("unroll") for (int kk_ = 0; kk_ < 2; ++kk_)                     \
            acc[(mq_) * 4 + i_][nq_] = __builtin_amdgcn_mfma_f32_16x16x32_bf16( \
                af[i_][kk_], bf[nq_][kk_], acc[(mq_) * 4 + i_][nq_], 0, 0, 0);  \
        __builtin_amdgcn_s_setprio(0);                                          \
        __builtin_amdgcn_s_barrier(); }

    // prologue: A0(0) B0(0) A1(0) B1(0) A0(1) B0(1)  (9 loads/thread)
    STA(0, 0, 0); STB(0, 0, 0); STA(0, 0, 1); STB(0, 0, 1);
    STA(1, 1, 0); STB(1, 1, 0);

    #pragma unroll 2
    for (int t = 0; t < 32; ++t) {
        const int b = t & 1;
        // gate: tile t fully landed; 3 newest loads (A0,B0 of t+1) stay in flight
        if (t < 31) { asm volatile("s_waitcnt vmcnt(3)" ::: "memory"); }
        else        { asm volatile("s_waitcnt vmcnt(0)" ::: "memory"); }
        __builtin_amdgcn_s_barrier();
        if (t < 31) STA(b ^ 1, t + 1, 1);       // p1: issue A1(t+1)
        LDA(0, b); LDB(0, b); MM(0, 0);
        if (t < 31) STB(b ^ 1, t + 1, 1);       // p2: issue B1(t+1)
        LDB(1, b); MM(0, 1);
        if (t < 30) STA(b, t + 2, 0);           // p3: issue A0(t+2)
        LDA(1, b); MM(1, 0);
        if (t < 30) STB(b, t + 2, 0);           // p4: issue B0(t+2)
        MM(1, 1);
    }

    // ---- epilogue ----
    #pragma unroll
    for (int fm = 0; fm < 8; ++fm) {
        #pragma unroll
        for (int fn = 0; fn < 2; ++fn) {
            const int col = n0 + wn * 32 + fn * 16 + l15;
            const int row0 = m0 + fm * 16 + l4 * 4;
            if (mode == 0) {
                const int z = col >> 11, c = col & 2047;
                const int h = c >> 7, d = c & 127;
                const float bb = (z == 0 ? bq : z == 1 ? bk : bv)[c];
                const int b_ = row0 >> 11, s = row0 & (SEQ - 1);
                if (z == 2) {
                    us4 pk;
                    #pragma unroll
                    for (int q = 0; q < 4; ++q) pk[q] = f2b(acc[fm][fn][q] + bb);
                    *(us4*)&Vb[(((size_t)(b_ * NHEADS + h)) * HDIM + d) * SEQ + s] = pk;
                } else {
                    u16* dst = (z ? Kb : Qb);
                    #pragma unroll
                    for (int q = 0; q < 4; ++q)
                        dst[(((size_t)(b_ * NHEADS + h)) * SEQ + s + q) * HDIM + d]
                            = f2b(acc[fm][fn][q] + bb);
                }
            } else {
                const float bb = bq[col];
                #pragma unroll
                for (int q = 0; q < 4; ++q)
                    Cf[(size_t)(row0 + q) * D_MODEL + col] = acc[fm][fn][q] + bb;
            }
        }
    }
    #undef STA
    #undef STB
    #undef LDA
    #undef LDB
    #undef MM
}

// ---------------------------------------------------------------------------
// RoPE table + apply. Q is additionally pre-scaled by 1/sqrt(HDIM).
// ---------------------------------------------------------------------------
__global__ void rope_table(float* __restrict__ tcos, float* __restrict__ tsin)
{
    const int idx = blockIdx.x * 256 + threadIdx.x;   // SEQ*64
    const int s = idx >> 6, i = idx & 63;
    const float inv = powf(10000.0f, -(float)i / 64.0f);
    const float ang = (float)s * inv;
    tcos[idx] = cosf(ang);
    tsin[idx] = sinf(ang);
}

__global__ void rope_apply(u16* __restrict__ Q, u16* __restrict__ K,
                           const float* __restrict__ tcos, const float* __restrict__ tsin)
{
    const int idx = blockIdx.x * 256 + threadIdx.x;
    u16* P = blockIdx.y ? K : Q;
    const float sc = blockIdx.y ? 1.0f : 0.08838834764831845f;  // 1/sqrt(128)
    const int i   = idx & 63;
    const int bhs = idx >> 6;
    const int s   = bhs & (SEQ - 1);
    const size_t base = (size_t)bhs * HDIM;
    const float x1 = b2f(P[base + i]), x2 = b2f(P[base + i + 64]);
    const float c  = tcos[(s << 6) + i], sn = tsin[(s << 6) + i];
    P[base + i]      = f2b((x1 * c  - x2 * sn) * sc);
    P[base + i + 64] = f2b((x1 * sn + x2 * c) * sc);
}

// ---------------------------------------------------------------------------
// MFMA flash attention v2 (+ setprio around MFMA clusters).
// Block = (b,h) x 128 q-rows; 4 waves x 32 q-rows. KV tile = 64.
// Swapped QK^T: s = mfma(K,Q) -> P-row in-lane. Double-buffered K/V staging.
// ---------------------------------------------------------------------------
__global__ __launch_bounds__(256, 2)
void flash_attn_mfma(const u16* __restrict__ Q, const u16* __restrict__ K,
                     const u16* __restrict__ Vt, u16* __restrict__ O)
{
    __shared__ __align__(16) u16 Ks[2][64 * 128];   // 2 x 16 KB
    __shared__ __align__(16) u16 Vs[2][128 * 64];   // 2 x 16 KB
    __shared__ __align__(16) u16 Ps[128 * 64];      // 16 KB  -> 80 KB total

    const int tid = threadIdx.x, lane = tid & 63, w = tid >> 6;
    const int l15 = lane & 15, l4 = lane >> 4;
    const int bh = blockIdx.y;
    const int qt = 15 - blockIdx.x;                 // descending workload
    const int q0 = qt * 128;
    const int qw = q0 + w * 32;                     // wave's 32 q rows
    const size_t baseQK = (size_t)bh * SEQ * HDIM;
    const size_t baseV  = (size_t)bh * HDIM * SEQ;

    short8 qf[2][4];
    #pragma unroll
    for (int u = 0; u < 2; ++u) {
        const u16* Qg = Q + baseQK + (size_t)(qw + u * 16 + l15) * HDIM;
        #pragma unroll
        for (int kk = 0; kk < 4; ++kk) qf[u][kk] = *(const short8*)&Qg[kk * 32 + l4 * 8];
    }

    floatx4 o_acc[2][8];
    #pragma unroll
    for (int u = 0; u < 2; ++u)
        #pragma unroll
        for (int j2 = 0; j2 < 8; ++j2) o_acc[u][j2] = (floatx4){0.f, 0.f, 0.f, 0.f};
    float m_run[2] = {-INFINITY, -INFINITY}, l_run[2] = {0.f, 0.f};

    const int nt = 2 * qt + 2;

    #define STAGE(buf, k0_)                                                     \
    {                                                                           \
        const u16* Kg = K  + baseQK + (size_t)(k0_) * HDIM;                     \
        const u16* Vg = Vt + baseV  + (k0_);                                    \
        _Pragma("unroll")                                                       \
        for (int p_ = 0; p_ < 4; ++p_) {                                        \
            const int idx = p_ * 256 + tid;                                     \
            const int r_ = idx >> 4, c_ = idx & 15;                             \
            const int srcK = (c_ & 8) | ((c_ & 7) ^ (r_ & 7));                  \
            async16(&Ks[buf][idx * 8], Kg + r_ * HDIM + srcK * 8);              \
            const int rv = idx >> 3, cv = idx & 7;                              \
            const int srcV = cv ^ (rv & 7);                                     \
            async16(&Vs[buf][idx * 8], Vg + (size_t)rv * SEQ + srcV * 8);       \
        }                                                                       \
    }

    STAGE(0, 0);
    __syncthreads();
    int cur = 0;

    for (int t = 0; t < nt; ++t) {
        if (t + 1 < nt) STAGE(cur ^ 1, (t + 1) * 64);

        floatx4 s[2][4];
        #pragma unroll
        for (int u = 0; u < 2; ++u)
            #pragma unroll
            for (int j = 0; j < 4; ++j) s[u][j] = (floatx4){0.f, 0.f, 0.f, 0.f};
        __builtin_amdgcn_s_setprio(1);
        #pragma unroll
        for (int j = 0; j < 4; ++j) {
            const int row = j * 16 + l15;
            #pragma unroll
            for (int kk = 0; kk < 4; ++kk) {
                const int x  = kk * 4 + l4;
                const int ch = (x & 8) | ((x & 7) ^ (row & 7));
                const short8 kf = *(const short8*)&Ks[cur][row * 128 + ch * 8];
                s[0][j] = __builtin_amdgcn_mfma_f32_16x16x32_bf16(kf, qf[0][kk], s[0][j], 0, 0, 0);
                s[1][j] = __builtin_amdgcn_mfma_f32_16x16x32_bf16(kf, qf[1][kk], s[1][j], 0, 0, 0);
            }
        }
        __builtin_amdgcn_s_setprio(0);

        if (t >= nt - 2) {
            const int k0 = t * 64;
            #pragma unroll
            for (int u = 0; u < 2; ++u) {
                const int qg = qw + u * 16 + l15;
                #pragma unroll
                for (int j = 0; j < 4; ++j)
                    #pragma unroll
                    for (int r = 0; r < 4; ++r)
                        if (k0 + j * 16 + l4 * 4 + r > qg) s[u][j][r] = -INFINITY;
            }
        }

        float al[2];
        #pragma unroll
        for (int u = 0; u < 2; ++u) {
            float m0_ = fmaxf(fmaxf(s[u][0][0], s[u][0][1]), fmaxf(s[u][0][2], s[u][0][3]));
            float m1_ = fmaxf(fmaxf(s[u][1][0], s[u][1][1]), fmaxf(s[u][1][2], s[u][1][3]));
            float m2_ = fmaxf(fmaxf(s[u][2][0], s[u][2][1]), fmaxf(s[u][2][2], s[u][2][3]));
            float m3_ = fmaxf(fmaxf(s[u][3][0], s[u][3][1]), fmaxf(s[u][3][2], s[u][3][3]));
            float mt = fmaxf(fmaxf(m0_, m1_), fmaxf(m2_, m3_));
            mt = fmaxf(mt, __shfl_xor(mt, 16));
            mt = fmaxf(mt, __shfl_xor(mt, 32));
            const float mn = fmaxf(m_run[u], mt);
            al[u] = __expf(m_run[u] - mn);
            m_run[u] = mn;
            const int prow = w * 32 + u * 16 + l15;
            const int swzp = (prow & 7) << 3;
            float rs = 0.f;
            #pragma unroll
            for (int j = 0; j < 4; ++j) {
                float p0 = __expf(s[u][j][0] - mn), p1 = __expf(s[u][j][1] - mn);
                float p2 = __expf(s[u][j][2] - mn), p3 = __expf(s[u][j][3] - mn);
                rs += (p0 + p1) + (p2 + p3);
                us4 pk; pk[0] = f2b(p0); pk[1] = f2b(p1); pk[2] = f2b(p2); pk[3] = f2b(p3);
                *(us4*)&Ps[prow * 64 + ((j * 16 + l4 * 4) ^ swzp)] = pk;
            }
            rs += __shfl_xor(rs, 16);
            rs += __shfl_xor(rs, 32);
            l_run[u] = l_run[u] * al[u] + rs;
        }

        #pragma unroll
        for (int u = 0; u < 2; ++u) {
            float alr[4];
            #pragma unroll
            for (int r = 0; r < 4; ++r) alr[r] = __shfl(al[u], l4 * 4 + r, 16);
            #pragma unroll
            for (int j2 = 0; j2 < 8; ++j2)
                #pragma unroll
                for (int r = 0; r < 4; ++r) o_acc[u][j2][r] *= alr[r];
        }

        __builtin_amdgcn_s_setprio(1);
        #pragma unroll
        for (int ks = 0; ks < 2; ++ks) {
            short8 pf[2];
            #pragma unroll
            for (int u = 0; u < 2; ++u) {
                const int prow = w * 32 + u * 16 + l15;
                pf[u] = *(const short8*)&Ps[prow * 64 + ((ks * 32 + l4 * 8) ^ ((prow & 7) << 3))];
            }
            #pragma unroll
            for (int j2 = 0; j2 < 8; ++j2) {
                const int vrow = j2 * 16 + l15;
                const int vch  = (ks * 4 + l4) ^ (vrow & 7);
                const short8 vf = *(const short8*)&Vs[cur][vrow * 64 + vch * 8];
                o_acc[0][j2] = __builtin_amdgcn_mfma_f32_16x16x32_bf16(pf[0], vf, o_acc[0][j2], 0, 0, 0);
                o_acc[1][j2] = __builtin_amdgcn_mfma_f32_16x16x32_bf16(pf[1], vf, o_acc[1][j2], 0, 0, 0);
            }
        }
        __builtin_amdgcn_s_setprio(0);

        __syncthreads();
        cur ^= 1;
    }

    const int b = bh >> 4, h = bh & 15;
    #pragma unroll
    for (int u = 0; u < 2; ++u) {
        const float invl = 1.f / l_run[u];
        float invr[4];
        #pragma unroll
        for (int r = 0; r < 4; ++r) invr[r] = __shfl(invl, l4 * 4 + r, 16);
        #pragma unroll
        for (int r = 0; r < 4; ++r) {
            const int s_ = qw + u * 16 + l4 * 4 + r;
            u16* dst = O + ((size_t)b * SEQ + s_) * D_MODEL + h * HDIM;
            #pragma unroll
            for (int j2 = 0; j2 < 8; ++j2)
                dst[j2 * 16 + l15] = f2b(o_acc[u][j2][r] * invr[r]);
        }
    }
    #undef STAGE
}

// ---------------------------------------------------------------------------
extern "C" void kernel_launch(void* const* d_in, const int* in_sizes, int n_in,
                              void* d_out, int out_size, void* d_ws, size_t ws_size,
                              hipStream_t stream)
{
    const float* x  = (const float*)d_in[0];
    const float* Wq = (const float*)d_in[2];
    const float* bq = (const float*)d_in[3];
    const float* Wk = (const float*)d_in[4];
    const float* bk = (const float*)d_in[5];
    const float* Wv = (const float*)d_in[6];
    const float* bv = (const float*)d_in[7];
    const float* Wo = (const float*)d_in[8];
    const float* bo = (const float*)d_in[9];
    float* out = (float*)d_out;

    const size_t TEN = (size_t)MTOT * D_MODEL;
    const size_t WEL = (size_t)D_MODEL * D_MODEL;
    char* p = (char*)d_ws;
    u16* xb  = (u16*)p; p += TEN * 2;
    u16* wqb = (u16*)p; p += WEL * 2;   // wqb,wkb,wvb contiguous => [6144][2048]
    u16* wkb = (u16*)p; p += WEL * 2;
    u16* wvb = (u16*)p; p += WEL * 2;
    u16* wob = (u16*)p; p += WEL * 2;
    u16* Qb  = (u16*)p; p += TEN * 2;
    u16* Kb  = (u16*)p; p += TEN * 2;
    u16* Vb  = (u16*)p; p += TEN * 2;   // transposed layout [B,H,Dh,S]
    u16* An  = (u16*)p; p += TEN * 2;
    float* tc = (float*)p; p += (size_t)SEQ * 64 * 4;
    float* ts = (float*)p;

    f2b_kernel<<<dim3(12288), 256, 0, stream>>>(x, Wq, Wk, Wv, Wo,
                                                xb, wqb, wkb, wvb, wob);
    rope_table<<<dim3(512), 256, 0, stream>>>(tc, ts);
    // fused QKV: N = 6144, grid = 24(n) x 32(m) = 768 blocks
    gemm8<<<dim3(768), 512, 0, stream>>>(xb, wqb, bq, bk, bv,
                                         Qb, Kb, Vb, nullptr, 0);
    rope_apply<<<dim3(16384, 2), 256, 0, stream>>>(Qb, Kb, tc, ts);
    flash_attn_mfma<<<dim3(16, 32), 256, 0, stream>>>(Qb, Kb, Vb, An);
    // O-proj: N = 2048, grid = 8(n) x 32(m) = 256 blocks; bf16 A, fp32 out
    gemm8<<<dim3(256), 512, 0, stream>>>(An, wob, bo, bo, bo,
                                         nullptr, nullptr, nullptr, out, 1);
}